// Round 11
// baseline (103.985 us; speedup 1.0000x reference)
//
#include <hip/hip_runtime.h>

#define EPS 1e-3f
#define SLOPE 0.01f
#define NBANK 16  // stats atomic spread banks

typedef __attribute__((ext_vector_type(8))) short s8v;
typedef __attribute__((ext_vector_type(4))) float f4v;

union U4S8 {
  uint4 u;
  s8v s;
};

static __device__ inline unsigned f2bf(float x) {  // RNE f32->bf16 (low 16)
  unsigned u = __float_as_uint(x);
  return (u + 0x7fffu + ((u >> 16) & 1u)) >> 16;
}
static __device__ inline float bf_lo(unsigned u) {
  return __uint_as_float(u << 16);
}
static __device__ inline float bf_hi(unsigned u) {
  return __uint_as_float(u & 0xffff0000u);
}

// ---------------------------------------------------------------------------
// prep kernel: fused {feature f32->bf16 convert | sums/zero-row/ctr init |
// K1 B-fragment table build}. One dispatch replaces three tiny ones.
// ---------------------------------------------------------------------------
__global__ __launch_bounds__(256) void prep_kernel(
    const float* __restrict__ features, uint4* __restrict__ fbf, int n8,
    const float* __restrict__ w1, const float* __restrict__ w2,
    uint4* __restrict__ tab, float* __restrict__ sums, uint4* __restrict__ r0,
    uint4* __restrict__ r1, uint4* __restrict__ r2, unsigned* __restrict__ ctr,
    int nc) {
  const int b = blockIdx.x;
  const int tid = threadIdx.x;
  if (b < nc) {  // cvt: features f32 -> bf16 rows
    int i = b * 256 + tid;
    if (i < n8) {
      const float4* p = (const float4*)features + (size_t)i * 2;
      float4 a = p[0], bb = p[1];
      uint4 o;
      o.x = f2bf(a.x) | (f2bf(a.y) << 16);
      o.y = f2bf(a.z) | (f2bf(a.w) << 16);
      o.z = f2bf(bb.x) | (f2bf(bb.y) << 16);
      o.w = f2bf(bb.z) | (f2bf(bb.w) << 16);
      fbf[i] = o;
    }
  } else if (b == nc) {  // init: stats accumulators + zero rows + sync ctr
#pragma unroll
    for (int i = 0; i < 16; i++) sums[i * 256 + tid] = 0.f;
    uint4 z = {0u, 0u, 0u, 0u};
    if (tid < 2) r0[tid] = z;
    else if (tid < 6) r1[tid - 2] = z;
    else if (tid < 10) r2[tid - 6] = z;
    else if (tid == 10) *ctr = 0u;
  } else if (tid < 64) {  // build K1 tables (20 slot-blocks)
    const int sb = b - nc - 1;  // 0..19
    const int conv = sb / 10, slot = sb % 10;
    const float* w = conv ? w2 : w1;
    const int T = slot >> 1, f = slot & 1;
    const int g = tid >> 4, c = tid & 15;
    s8v t;
#pragma unroll
    for (int j = 0; j < 8; j++) {
      int kl = g * 8 + j;
      int tap = 2 * T + (kl >> 4);
      int ci = kl & 15;
      t[j] = (short)(tap < 9 ? f2bf(w[(tap * 16 + ci) * 32 + 2 * c + f]) : 0);
    }
    U4S8 u;
    u.s = t;
    tab[(conv * 10 + slot) * 64 + tid] = u.u;
  }
}

// ---------------------------------------------------------------------------
// MFMA subm-conv, R25: R23 structure (verified 69.83us best) + the
// build_tab_k2 dispatch folded into K1's tail via the LAST-BLOCK pattern:
// after stats atomics, tid0 fetch_add(ctr, ACQ_REL, AGENT); the block
// observing gridDim.x-1 (acquire synchronizes-with all prior releases --
// the protocol HW-proven in R16/R21) computes both BN-folded K2 tables and
// writes them to global; kernel-boundary coherence publishes them to K2.
// No spin, no co-residency need; K1 main loop untouched; K2 instantiation
// (DOTAB=false) codegen-identical to R23. Removes one dispatch + one gap.
// Per tile: idx load -> UNCONDITIONAL gathers (dead slots read maintained
// zero row n; static schedule => counted vmcnt) -> slot-skipped MFMAs.
// ---------------------------------------------------------------------------
template <bool PAIRED, int TPWK, bool DOTAB>
__global__ __launch_bounds__(256, 4) void conv_mfma(
    const unsigned short* __restrict__ src0, const int* __restrict__ nbr0,
    const uint4* __restrict__ tab0, unsigned short* __restrict__ dst0,
    float* __restrict__ osums0, const unsigned short* __restrict__ src1,
    const int* __restrict__ nbr1, const uint4* __restrict__ tab1,
    unsigned short* __restrict__ dst1, float* __restrict__ osums1, int n,
    int gb, const float* __restrict__ w12, const float* __restrict__ w3,
    const float* __restrict__ g0, const float* __restrict__ b0,
    const float* __restrict__ g1, const float* __restrict__ b1,
    uint4* __restrict__ tabk2, unsigned* __restrict__ ctr) {
  constexpr int NS = PAIRED ? 5 : 9;      // mfma slots per tile
  constexpr int NSLOT = PAIRED ? 10 : 20; // table slots
  __shared__ uint4 bwl[NSLOT * 64];
  __shared__ float redl[4 * 64];

  const int tid = threadIdx.x;
  const bool second = (int)blockIdx.x >= gb;
  const unsigned short* src = second ? src1 : src0;
  const int* nbr = second ? nbr1 : nbr0;
  const uint4* tab = second ? tab1 : tab0;
  unsigned short* dst = second ? dst1 : dst0;
  float* osums = second ? osums1 : osums0;

  // stage table global -> LDS (coalesced)
  for (int i = tid; i < NSLOT * 64; i += 256) bwl[i] = tab[i];
  __syncthreads();

  const int lane = tid & 63;
  const int wv = tid >> 6;
  const int g = lane >> 4;  // k-chunk group 0..3
  const int c = lane & 15;  // A row (point) / B col index (cout pair c)

  s8v bbias0, bbias1;
  if (!PAIRED) {
    U4S8 x;
    x.u = bwl[18 * 64 + lane];
    bbias0 = x.s;
    x.u = bwl[19 * 64 + lane];
    bbias1 = x.s;
  }

  const int bid = second ? (int)blockIdx.x - gb : (int)blockIdx.x;
  const int wbase = bid * (64 * TPWK) + wv * (16 * TPWK);

  float s0 = 0.f, s1 = 0.f, q0 = 0.f, q1 = 0.f;  // stats accumulators

#pragma unroll 1
  for (int t = 0; t < TPWK; t++) {
    const int pbase = wbase + t * 16;

    // ---- tile indices (coalesced; per-lane point pbase+c) ----
    int jj[9];
    {
      int pt = pbase + c;
      bool a = pt < n;
#pragma unroll
      for (int k = 0; k < 9; k++) jj[k] = a ? nbr[(size_t)k * n + pt] : -1;
    }

    // ---- UNCONDITIONAL gathers (dead lanes read zero row n: L1-hot line,
    //      broadcast within c-group; static schedule => counted vmcnt) ----
    uint4 ga[NS];
#pragma unroll
    for (int s = 0; s < NS; s++) {
      int jr;
      if (PAIRED) {
        int jA = jj[2 * s];
        int jB = jj[(2 * s + 1 < 9) ? 2 * s + 1 : 8];
        jr = (g & 2) ? jB : jA;
      } else {
        jr = jj[s];
      }
      unsigned jc = jr < 0 ? (unsigned)n : (unsigned)jr;  // zero row
      ga[s] = ((const uint4*)src)[PAIRED ? ((size_t)jc * 2 + (g & 1))
                                         : ((size_t)jc * 4 + g)];
    }

    // ---- per-slot wave-uniform validity (ballot -> scalar MFMA skip) ----
    unsigned vmask = 0;
    if (!PAIRED) {
#pragma unroll
      for (int k = 0; k < 9; k++) vmask |= (jj[k] >= 0 ? 1u : 0u) << k;
    }
    unsigned son = 0;
#pragma unroll
    for (int s = 0; s < NS; s++) {
      bool on;
      if (PAIRED) {
        int jA = jj[2 * s];
        int jB = jj[(2 * s + 1 < 9) ? 2 * s + 1 : 8];
        on = __ballot(jA >= 0 || jB >= 0) != 0ull;
      } else {
        on = __ballot(jj[s] >= 0) != 0ull;
      }
      son |= (on ? 1u : 0u) << s;
    }

    // ---- MFMA accumulate (live slots only) ----
    f4v acc0 = {0.f, 0.f, 0.f, 0.f};
    f4v acc1 = {0.f, 0.f, 0.f, 0.f};
#pragma unroll
    for (int s = 0; s < NS; s++) {
      if (son & (1u << s)) {  // wave-uniform scalar branch
        U4S8 a;
        a.u = ga[s];
        U4S8 b0, b1;
        b0.u = bwl[(s * 2 + 0) * 64 + lane];
        b1.u = bwl[(s * 2 + 1) * 64 + lane];
        acc0 = __builtin_amdgcn_mfma_f32_16x16x32_bf16(a.s, b0.s, acc0, 0, 0, 0);
        acc1 = __builtin_amdgcn_mfma_f32_16x16x32_bf16(a.s, b1.s, acc1, 0, 0, 0);
      }
    }
    if (!PAIRED) {  // bias via validity-matrix MFMA (covers all taps)
      s8v av;
#pragma unroll
      for (int j = 0; j < 8; j++) {
        unsigned kk = (unsigned)(g * 8 + j);
        unsigned bit = (kk < 32u) ? ((vmask >> kk) & 1u) : 0u;
        av[j] = (short)(bit ? 0x3F80 : 0);
      }
      acc0 = __builtin_amdgcn_mfma_f32_16x16x32_bf16(av, bbias0, acc0, 0, 0, 0);
      acc1 = __builtin_amdgcn_mfma_f32_16x16x32_bf16(av, bbias1, acc1, 0, 0, 0);
    }

    // ---- lrelu + stats ----
#pragma unroll
    for (int r = 0; r < 4; r++) {
      float x = acc0[r];
      x = fmaxf(x, SLOPE * x);
      acc0[r] = x;
      s0 += x;
      q0 = fmaf(x, x, q0);
      float y = acc1[r];
      y = fmaxf(y, SLOPE * y);
      acc1[r] = y;
      s1 += y;
      q1 = fmaf(y, y, q1);
    }

    // ---- direct coalesced store: lane (g,c) owns points pbase+g*4+r,
    //      couts (2c,2c+1) -> one packed bf16x2 dword each ----
#pragma unroll
    for (int r = 0; r < 4; r++) {
      int p = pbase + g * 4 + r;
      if (p < n)
        ((unsigned*)dst)[(size_t)p * 16 + c] =
            f2bf(acc0[r]) | (f2bf(acc1[r]) << 16);
    }
  }

  // ---- block stats reduction, one atomic per channel into spread bank ----
  s0 += __shfl_xor(s0, 16, 64);
  s0 += __shfl_xor(s0, 32, 64);
  s1 += __shfl_xor(s1, 16, 64);
  s1 += __shfl_xor(s1, 32, 64);
  q0 += __shfl_xor(q0, 16, 64);
  q0 += __shfl_xor(q0, 32, 64);
  q1 += __shfl_xor(q1, 16, 64);
  q1 += __shfl_xor(q1, 32, 64);
  if (lane < 16) {
    redl[wv * 64 + 2 * c] = s0;
    redl[wv * 64 + 2 * c + 1] = s1;
    redl[wv * 64 + 32 + 2 * c] = q0;
    redl[wv * 64 + 32 + 2 * c + 1] = q1;
  }
  __syncthreads();
  if (tid < 64) {
    float t = redl[tid] + redl[64 + tid] + redl[128 + tid] + redl[192 + tid];
    atomicAdd(&osums[(bid & (NBANK - 1)) * 64 + tid], t);
  }

  if (DOTAB) {
    // ---- last-block tail: build the BN-folded K2 tables ----
    __syncthreads();  // block's atomicAdds precede tid0's release
    if (tid == 0) {
      unsigned v = __hip_atomic_fetch_add(ctr, 1u, __ATOMIC_ACQ_REL,
                                          __HIP_MEMORY_SCOPE_AGENT);
      redl[0] = (v == gridDim.x - 1) ? 1.0f : 0.0f;
    }
    __syncthreads();
    if (redl[0] != 0.0f) {  // block-uniform: only the LAST block proceeds
      float* stl = &redl[64];  // stl[conv*64 + {0..31 scale, 32..63 offset}]
      if (tid < 64) {
        int cv = tid >> 5;
        int ln = tid & 31;
        const float* sums = cv ? osums1 : osums0;
        float ssum = 0.f, qsum = 0.f;
#pragma unroll
        for (int bk = 0; bk < NBANK; bk++) {  // agent-scope loads: fresh
          ssum += __hip_atomic_load(&sums[bk * 64 + ln], __ATOMIC_RELAXED,
                                    __HIP_MEMORY_SCOPE_AGENT);
          qsum += __hip_atomic_load(&sums[bk * 64 + 32 + ln], __ATOMIC_RELAXED,
                                    __HIP_MEMORY_SCOPE_AGENT);
        }
        float inv_n = 1.0f / (float)n;
        float m = ssum * inv_n;
        float vv = qsum * inv_n - m * m;
        float s = (cv ? g1 : g0)[ln] * rsqrtf(vv + EPS);
        stl[cv * 64 + ln] = s;
        stl[cv * 64 + 32 + ln] = (cv ? b1 : b0)[ln] - m * s;
      }
      __syncthreads();
#pragma unroll 1
      for (int sb = wv; sb < 40; sb += 4) {  // 4 waves cover 40 slot-blocks
        int cv = sb / 20, slot = sb % 20;
        const float* w = cv ? w3 : w12;
        const float* sp = &stl[cv * 64];
        int gg = lane >> 4, cc = lane & 15;
        s8v t;
        if (slot < 18) {
          int k = slot >> 1, f = slot & 1;
#pragma unroll
          for (int j = 0; j < 8; j++) {
            int ci = gg * 8 + j;
            t[j] = (short)f2bf(w[(k * 32 + ci) * 32 + 2 * cc + f] * sp[ci]);
          }
        } else {
          int f = slot - 18;
#pragma unroll
          for (int j = 0; j < 8; j++) {
            int kk = gg * 8 + j;
            if (kk < 9) {
              float a = 0.f;
              for (int ci = 0; ci < 32; ci++)
                a += sp[32 + ci] * w[(kk * 32 + ci) * 32 + 2 * cc + f];
              t[j] = (short)f2bf(a);
            } else {
              t[j] = 0;
            }
          }
        }
        U4S8 u;
        u.s = t;
        tabk2[(cv * 20 + slot) * 64 + lane] = u.u;
      }
    }
  }
}

// out = bnA(z12) + bnB(z3), both inputs bf16 [n][32]; sums are NBANK-spread
__global__ __launch_bounds__(256) void final_kernel(
    const uint4* __restrict__ z12, const uint4* __restrict__ z3,
    float* __restrict__ out, const float* __restrict__ sumsA,
    const float* __restrict__ gA, const float* __restrict__ bA,
    const float* __restrict__ sumsB, const float* __restrict__ gB,
    const float* __restrict__ bB, int n) {
  __shared__ float st[128];  // sA tA sB tB
  const int tid = threadIdx.x;
  if (tid < 32) {
    float sa = 0.f, qa = 0.f, sb = 0.f, qb = 0.f;
#pragma unroll
    for (int bk = 0; bk < NBANK; bk++) {
      sa += sumsA[bk * 64 + tid];
      qa += sumsA[bk * 64 + 32 + tid];
      sb += sumsB[bk * 64 + tid];
      qb += sumsB[bk * 64 + 32 + tid];
    }
    float inv_n = 1.0f / (float)n;
    float m = sa * inv_n;
    float v = qa * inv_n - m * m;
    float s = gA[tid] * rsqrtf(v + EPS);
    st[tid] = s;
    st[32 + tid] = bA[tid] - m * s;
    m = sb * inv_n;
    v = qb * inv_n - m * m;
    s = gB[tid] * rsqrtf(v + EPS);
    st[64 + tid] = s;
    st[96 + tid] = bB[tid] - m * s;
  }
  __syncthreads();
  const int total = n * 4;  // 8-channel chunks
  for (int i = blockIdx.x * 256 + tid; i < total; i += gridDim.x * 256) {
    int c0 = (i & 3) * 8;
    uint4 a = z12[i], b = z3[i];
    float4 r0, r1;
    r0.x = bf_lo(a.x) * st[c0 + 0] + st[32 + c0 + 0] + bf_lo(b.x) * st[64 + c0 + 0] + st[96 + c0 + 0];
    r0.y = bf_hi(a.x) * st[c0 + 1] + st[32 + c0 + 1] + bf_hi(b.x) * st[64 + c0 + 1] + st[96 + c0 + 1];
    r0.z = bf_lo(a.y) * st[c0 + 2] + st[32 + c0 + 2] + bf_lo(b.y) * st[64 + c0 + 2] + st[96 + c0 + 2];
    r0.w = bf_hi(a.y) * st[c0 + 3] + st[32 + c0 + 3] + bf_hi(b.y) * st[64 + c0 + 3] + st[96 + c0 + 3];
    r1.x = bf_lo(a.z) * st[c0 + 4] + st[32 + c0 + 4] + bf_lo(b.z) * st[64 + c0 + 4] + st[96 + c0 + 4];
    r1.y = bf_hi(a.z) * st[c0 + 5] + st[32 + c0 + 5] + bf_hi(b.z) * st[64 + c0 + 5] + st[96 + c0 + 5];
    r1.z = bf_lo(a.w) * st[c0 + 6] + st[32 + c0 + 6] + bf_lo(b.w) * st[64 + c0 + 6] + st[96 + c0 + 6];
    r1.w = bf_hi(a.w) * st[c0 + 7] + st[32 + c0 + 7] + bf_hi(b.w) * st[64 + c0 + 7] + st[96 + c0 + 7];
    ((float4*)out)[2 * i + 0] = r0;
    ((float4*)out)[2 * i + 1] = r1;
  }
}

extern "C" void kernel_launch(void* const* d_in, const int* in_sizes, int n_in,
                              void* d_out, int out_size, void* d_ws,
                              size_t ws_size, hipStream_t stream) {
  const float* features = (const float*)d_in[0];
  const int* nbr133 = (const int*)d_in[1];
  const int* nbr313 = (const int*)d_in[2];
  const float* conv1_w = (const float*)d_in[3];
  const float* conv12_w = (const float*)d_in[4];
  const float* conv2_w = (const float*)d_in[5];
  const float* conv3_w = (const float*)d_in[6];
  const float* bn0_g = (const float*)d_in[7];
  const float* bn0_b = (const float*)d_in[8];
  const float* bn02_g = (const float*)d_in[9];
  const float* bn02_b = (const float*)d_in[10];
  const float* bn1_g = (const float*)d_in[11];
  const float* bn1_b = (const float*)d_in[12];
  const float* bn2_g = (const float*)d_in[13];
  const float* bn2_b = (const float*)d_in[14];
  float* out = (float*)d_out;

  const int n = in_sizes[0] / 16;  // 250000
  char* ws = (char*)d_ws;
  const size_t A = (size_t)n * 64 + 64;  // bf16 [n+1][32] region

  // region0: fbf ([n+1][16] bf16) overlaid later by z12 ([n][32] bf16)
  unsigned short* fbf = (unsigned short*)ws;
  unsigned short* z12 = (unsigned short*)ws;
  unsigned short* zA1 = (unsigned short*)(ws + A);
  unsigned short* zA2 = (unsigned short*)(ws + 2 * A);
  unsigned short* z3 = (unsigned short*)(ws + 3 * A);
  float* sums = (float*)(ws + 4 * A);
  // sums: 4 stat sets x NBANK banks x 64 floats:
  //   +0 z1 | +1024 z2 | +2048 z12 | +3072 z3
  uint4* tabK1 = (uint4*)(ws + 4 * A + 4 * NBANK * 64 * 4);
  uint4* tabK2 = tabK1 + 20 * 64;
  unsigned* ctr = (unsigned*)(tabK2 + 40 * 64);

  const int n8 = n * 2;  // 8-float chunks of features
  const int nc = (n8 + 255) / 256;
  // fused prep: cvt | init | tabK1 build
  prep_kernel<<<nc + 21, 256, 0, stream>>>(
      features, (uint4*)fbf, n8, conv1_w, conv2_w, tabK1, sums,
      (uint4*)(ws + (size_t)n * 32),            // fbf row n
      (uint4*)(ws + A + (size_t)n * 64),        // zA1 row n
      (uint4*)(ws + 2 * A + (size_t)n * 64),    // zA2 row n
      ctr, nc);

  const int gb = (n + 511) / 512;  // TPW=8: 512 pts/block (both convs)
  // K1: conv1 (fbf,nbr133)->zA1 || conv2 (fbf,nbr313)->zA2; last block
  // builds tabK2 (BN of K1 folded in) in its tail.
  conv_mfma<true, 8, true><<<2 * gb, 256, 0, stream>>>(
      fbf, nbr133, tabK1, zA1, sums + 0, fbf, nbr313, tabK1 + 10 * 64, zA2,
      sums + 1024, n, gb, conv12_w, conv3_w, bn0_g, bn0_b, bn1_g, bn1_b,
      tabK2, ctr);
  // K2: conv12 (bn0(zA1),nbr313)->z12 || conv3 (bn1(zA2),nbr133)->z3
  conv_mfma<false, 8, false><<<2 * gb, 256, 0, stream>>>(
      zA1, nbr313, tabK2, z12, sums + 2048, zA2, nbr133, tabK2 + 20 * 64, z3,
      sums + 3072, n, gb, (const float*)nullptr, (const float*)nullptr,
      (const float*)nullptr, (const float*)nullptr, (const float*)nullptr,
      (const float*)nullptr, (uint4*)nullptr, (unsigned*)nullptr);
  // out = bn02(z12) + bn2(z3)
  final_kernel<<<1024, 256, 0, stream>>>((const uint4*)z12, (const uint4*)z3,
                                         out, sums + 2048, bn02_g, bn02_b,
                                         sums + 3072, bn2_g, bn2_b, n);
}

// Round 12
// 69.916 us; speedup vs baseline: 1.4873x; 1.4873x over previous
//
#include <hip/hip_runtime.h>

#define EPS 1e-3f
#define SLOPE 0.01f
#define NBANK 16  // stats atomic spread banks

typedef __attribute__((ext_vector_type(8))) short s8v;
typedef __attribute__((ext_vector_type(4))) float f4v;

union U4S8 {
  uint4 u;
  s8v s;
};

static __device__ inline unsigned f2bf(float x) {  // RNE f32->bf16 (low 16)
  unsigned u = __float_as_uint(x);
  return (u + 0x7fffu + ((u >> 16) & 1u)) >> 16;
}
static __device__ inline float bf_lo(unsigned u) {
  return __uint_as_float(u << 16);
}
static __device__ inline float bf_hi(unsigned u) {
  return __uint_as_float(u & 0xffff0000u);
}

// ---------------------------------------------------------------------------
// prep kernel: fused {feature f32->bf16 convert | sums/zero-row init |
// K1 B-fragment table build}. One dispatch replaces three tiny ones.
// ---------------------------------------------------------------------------
__global__ __launch_bounds__(256) void prep_kernel(
    const float* __restrict__ features, uint4* __restrict__ fbf, int n8,
    const float* __restrict__ w1, const float* __restrict__ w2,
    uint4* __restrict__ tab, float* __restrict__ sums, uint4* __restrict__ r0,
    uint4* __restrict__ r1, uint4* __restrict__ r2, int nc) {
  const int b = blockIdx.x;
  const int tid = threadIdx.x;
  if (b < nc) {  // cvt: features f32 -> bf16 rows
    int i = b * 256 + tid;
    if (i < n8) {
      const float4* p = (const float4*)features + (size_t)i * 2;
      float4 a = p[0], bb = p[1];
      uint4 o;
      o.x = f2bf(a.x) | (f2bf(a.y) << 16);
      o.y = f2bf(a.z) | (f2bf(a.w) << 16);
      o.z = f2bf(bb.x) | (f2bf(bb.y) << 16);
      o.w = f2bf(bb.z) | (f2bf(bb.w) << 16);
      fbf[i] = o;
    }
  } else if (b == nc) {  // init: stats accumulators + zero rows
#pragma unroll
    for (int i = 0; i < 16; i++) sums[i * 256 + tid] = 0.f;
    uint4 z = {0u, 0u, 0u, 0u};
    if (tid < 2) r0[tid] = z;
    else if (tid < 6) r1[tid - 2] = z;
    else if (tid < 10) r2[tid - 6] = z;
  } else if (tid < 64) {  // build K1 tables (20 slot-blocks)
    const int sb = b - nc - 1;  // 0..19
    const int conv = sb / 10, slot = sb % 10;
    const float* w = conv ? w2 : w1;
    const int T = slot >> 1, f = slot & 1;
    const int g = tid >> 4, c = tid & 15;
    s8v t;
#pragma unroll
    for (int j = 0; j < 8; j++) {
      int kl = g * 8 + j;
      int tap = 2 * T + (kl >> 4);
      int ci = kl & 15;
      t[j] = (short)(tap < 9 ? f2bf(w[(tap * 16 + ci) * 32 + 2 * c + f]) : 0);
    }
    U4S8 u;
    u.s = t;
    tab[(conv * 10 + slot) * 64 + tid] = u.u;
  }
}

__global__ __launch_bounds__(64) void build_tab_k2(
    const float* __restrict__ w12, const float* __restrict__ w3,
    const float* __restrict__ sums1, const float* __restrict__ sums2,
    const float* __restrict__ g0, const float* __restrict__ b0,
    const float* __restrict__ g1, const float* __restrict__ b1,
    uint4* __restrict__ tab, int n) {
  __shared__ float stl[64];
  const int conv = blockIdx.x / 20, slot = blockIdx.x % 20;
  const float* w = conv ? w3 : w12;
  const float* sums = conv ? sums2 : sums1;
  const float* bn_g = conv ? g1 : g0;
  const float* bn_b = conv ? b1 : b0;
  const int lane = threadIdx.x;
  if (lane < 32) {
    float ssum = 0.f, qsum = 0.f;
#pragma unroll
    for (int bk = 0; bk < NBANK; bk++) {  // reduce spread banks
      ssum += sums[bk * 64 + lane];
      qsum += sums[bk * 64 + 32 + lane];
    }
    float inv_n = 1.0f / (float)n;
    float m = ssum * inv_n;
    float v = qsum * inv_n - m * m;
    float s = bn_g[lane] * rsqrtf(v + EPS);
    stl[lane] = s;
    stl[32 + lane] = bn_b[lane] - m * s;
  }
  __syncthreads();
  const int g = lane >> 4, c = lane & 15;
  s8v t;
  if (slot < 18) {
    const int k = slot >> 1, f = slot & 1;
#pragma unroll
    for (int j = 0; j < 8; j++) {
      int ci = g * 8 + j;
      t[j] = (short)f2bf(w[(k * 32 + ci) * 32 + 2 * c + f] * stl[ci]);
    }
  } else {
    const int f = slot - 18;
#pragma unroll
    for (int j = 0; j < 8; j++) {
      int kk = g * 8 + j;
      if (kk < 9) {
        float a = 0.f;
        for (int ci = 0; ci < 32; ci++)
          a += stl[32 + ci] * w[(kk * 32 + ci) * 32 + 2 * c + f];
        t[j] = (short)f2bf(a);
      } else {
        t[j] = 0;
      }
    }
  }
  U4S8 u;
  u.s = t;
  tab[(conv * 20 + slot) * 64 + lane] = u.u;
}

// ---------------------------------------------------------------------------
// MFMA subm-conv, R26 = exact R23 revert (verified 69.83us best). R25's
// last-block tab-build tail collapsed the allocator to 48 VGPR (third
// occurrence of the signature: R16 zheld, R21 fused epilogue, R25 DOTAB
// tail) -- the conv kernel must stay EXACTLY this shape so the compiler
// grants ~100 VGPR and keeps all 9 gathers concurrently in flight.
// Both convs TPW=8 (block-amortization lever, +1.7us over TPW=4), (256,4)
// occupancy, unconditional gathers (dead slots read maintained zero row n;
// static schedule => counted vmcnt), slot-skipped MFMAs.
// ---------------------------------------------------------------------------
template <bool PAIRED, int TPWK>
__global__ __launch_bounds__(256, 4) void conv_mfma(
    const unsigned short* __restrict__ src0, const int* __restrict__ nbr0,
    const uint4* __restrict__ tab0, unsigned short* __restrict__ dst0,
    float* __restrict__ osums0, const unsigned short* __restrict__ src1,
    const int* __restrict__ nbr1, const uint4* __restrict__ tab1,
    unsigned short* __restrict__ dst1, float* __restrict__ osums1, int n,
    int gb) {
  constexpr int NS = PAIRED ? 5 : 9;      // mfma slots per tile
  constexpr int NSLOT = PAIRED ? 10 : 20; // table slots
  __shared__ uint4 bwl[NSLOT * 64];
  __shared__ float redl[4 * 64];

  const int tid = threadIdx.x;
  const bool second = (int)blockIdx.x >= gb;
  const unsigned short* src = second ? src1 : src0;
  const int* nbr = second ? nbr1 : nbr0;
  const uint4* tab = second ? tab1 : tab0;
  unsigned short* dst = second ? dst1 : dst0;
  float* osums = second ? osums1 : osums0;

  // stage table global -> LDS (coalesced)
  for (int i = tid; i < NSLOT * 64; i += 256) bwl[i] = tab[i];
  __syncthreads();

  const int lane = tid & 63;
  const int wv = tid >> 6;
  const int g = lane >> 4;  // k-chunk group 0..3
  const int c = lane & 15;  // A row (point) / B col index (cout pair c)

  s8v bbias0, bbias1;
  if (!PAIRED) {
    U4S8 x;
    x.u = bwl[18 * 64 + lane];
    bbias0 = x.s;
    x.u = bwl[19 * 64 + lane];
    bbias1 = x.s;
  }

  const int bid = second ? (int)blockIdx.x - gb : (int)blockIdx.x;
  const int wbase = bid * (64 * TPWK) + wv * (16 * TPWK);

  float s0 = 0.f, s1 = 0.f, q0 = 0.f, q1 = 0.f;  // stats accumulators

#pragma unroll 1
  for (int t = 0; t < TPWK; t++) {
    const int pbase = wbase + t * 16;

    // ---- tile indices (coalesced; per-lane point pbase+c) ----
    int jj[9];
    {
      int pt = pbase + c;
      bool a = pt < n;
#pragma unroll
      for (int k = 0; k < 9; k++) jj[k] = a ? nbr[(size_t)k * n + pt] : -1;
    }

    // ---- UNCONDITIONAL gathers (dead lanes read zero row n: L1-hot line,
    //      broadcast within c-group; static schedule => counted vmcnt) ----
    uint4 ga[NS];
#pragma unroll
    for (int s = 0; s < NS; s++) {
      int jr;
      if (PAIRED) {
        int jA = jj[2 * s];
        int jB = jj[(2 * s + 1 < 9) ? 2 * s + 1 : 8];
        jr = (g & 2) ? jB : jA;
      } else {
        jr = jj[s];
      }
      unsigned jc = jr < 0 ? (unsigned)n : (unsigned)jr;  // zero row
      ga[s] = ((const uint4*)src)[PAIRED ? ((size_t)jc * 2 + (g & 1))
                                         : ((size_t)jc * 4 + g)];
    }

    // ---- per-slot wave-uniform validity (ballot -> scalar MFMA skip) ----
    unsigned vmask = 0;
    if (!PAIRED) {
#pragma unroll
      for (int k = 0; k < 9; k++) vmask |= (jj[k] >= 0 ? 1u : 0u) << k;
    }
    unsigned son = 0;
#pragma unroll
    for (int s = 0; s < NS; s++) {
      bool on;
      if (PAIRED) {
        int jA = jj[2 * s];
        int jB = jj[(2 * s + 1 < 9) ? 2 * s + 1 : 8];
        on = __ballot(jA >= 0 || jB >= 0) != 0ull;
      } else {
        on = __ballot(jj[s] >= 0) != 0ull;
      }
      son |= (on ? 1u : 0u) << s;
    }

    // ---- MFMA accumulate (live slots only) ----
    f4v acc0 = {0.f, 0.f, 0.f, 0.f};
    f4v acc1 = {0.f, 0.f, 0.f, 0.f};
#pragma unroll
    for (int s = 0; s < NS; s++) {
      if (son & (1u << s)) {  // wave-uniform scalar branch
        U4S8 a;
        a.u = ga[s];
        U4S8 b0, b1;
        b0.u = bwl[(s * 2 + 0) * 64 + lane];
        b1.u = bwl[(s * 2 + 1) * 64 + lane];
        acc0 = __builtin_amdgcn_mfma_f32_16x16x32_bf16(a.s, b0.s, acc0, 0, 0, 0);
        acc1 = __builtin_amdgcn_mfma_f32_16x16x32_bf16(a.s, b1.s, acc1, 0, 0, 0);
      }
    }
    if (!PAIRED) {  // bias via validity-matrix MFMA (covers all taps)
      s8v av;
#pragma unroll
      for (int j = 0; j < 8; j++) {
        unsigned kk = (unsigned)(g * 8 + j);
        unsigned bit = (kk < 32u) ? ((vmask >> kk) & 1u) : 0u;
        av[j] = (short)(bit ? 0x3F80 : 0);
      }
      acc0 = __builtin_amdgcn_mfma_f32_16x16x32_bf16(av, bbias0, acc0, 0, 0, 0);
      acc1 = __builtin_amdgcn_mfma_f32_16x16x32_bf16(av, bbias1, acc1, 0, 0, 0);
    }

    // ---- lrelu + stats ----
#pragma unroll
    for (int r = 0; r < 4; r++) {
      float x = acc0[r];
      x = fmaxf(x, SLOPE * x);
      acc0[r] = x;
      s0 += x;
      q0 = fmaf(x, x, q0);
      float y = acc1[r];
      y = fmaxf(y, SLOPE * y);
      acc1[r] = y;
      s1 += y;
      q1 = fmaf(y, y, q1);
    }

    // ---- direct coalesced store: lane (g,c) owns points pbase+g*4+r,
    //      couts (2c,2c+1) -> one packed bf16x2 dword each ----
#pragma unroll
    for (int r = 0; r < 4; r++) {
      int p = pbase + g * 4 + r;
      if (p < n)
        ((unsigned*)dst)[(size_t)p * 16 + c] =
            f2bf(acc0[r]) | (f2bf(acc1[r]) << 16);
    }
  }

  // ---- block stats reduction, one atomic per channel into spread bank ----
  s0 += __shfl_xor(s0, 16, 64);
  s0 += __shfl_xor(s0, 32, 64);
  s1 += __shfl_xor(s1, 16, 64);
  s1 += __shfl_xor(s1, 32, 64);
  q0 += __shfl_xor(q0, 16, 64);
  q0 += __shfl_xor(q0, 32, 64);
  q1 += __shfl_xor(q1, 16, 64);
  q1 += __shfl_xor(q1, 32, 64);
  if (lane < 16) {
    redl[wv * 64 + 2 * c] = s0;
    redl[wv * 64 + 2 * c + 1] = s1;
    redl[wv * 64 + 32 + 2 * c] = q0;
    redl[wv * 64 + 32 + 2 * c + 1] = q1;
  }
  __syncthreads();
  if (tid < 64) {
    float t = redl[tid] + redl[64 + tid] + redl[128 + tid] + redl[192 + tid];
    atomicAdd(&osums[(bid & (NBANK - 1)) * 64 + tid], t);
  }
}

// out = bnA(z12) + bnB(z3), both inputs bf16 [n][32]; sums are NBANK-spread
__global__ __launch_bounds__(256) void final_kernel(
    const uint4* __restrict__ z12, const uint4* __restrict__ z3,
    float* __restrict__ out, const float* __restrict__ sumsA,
    const float* __restrict__ gA, const float* __restrict__ bA,
    const float* __restrict__ sumsB, const float* __restrict__ gB,
    const float* __restrict__ bB, int n) {
  __shared__ float st[128];  // sA tA sB tB
  const int tid = threadIdx.x;
  if (tid < 32) {
    float sa = 0.f, qa = 0.f, sb = 0.f, qb = 0.f;
#pragma unroll
    for (int bk = 0; bk < NBANK; bk++) {
      sa += sumsA[bk * 64 + tid];
      qa += sumsA[bk * 64 + 32 + tid];
      sb += sumsB[bk * 64 + tid];
      qb += sumsB[bk * 64 + 32 + tid];
    }
    float inv_n = 1.0f / (float)n;
    float m = sa * inv_n;
    float v = qa * inv_n - m * m;
    float s = gA[tid] * rsqrtf(v + EPS);
    st[tid] = s;
    st[32 + tid] = bA[tid] - m * s;
    m = sb * inv_n;
    v = qb * inv_n - m * m;
    s = gB[tid] * rsqrtf(v + EPS);
    st[64 + tid] = s;
    st[96 + tid] = bB[tid] - m * s;
  }
  __syncthreads();
  const int total = n * 4;  // 8-channel chunks
  for (int i = blockIdx.x * 256 + tid; i < total; i += gridDim.x * 256) {
    int c0 = (i & 3) * 8;
    uint4 a = z12[i], b = z3[i];
    float4 r0, r1;
    r0.x = bf_lo(a.x) * st[c0 + 0] + st[32 + c0 + 0] + bf_lo(b.x) * st[64 + c0 + 0] + st[96 + c0 + 0];
    r0.y = bf_hi(a.x) * st[c0 + 1] + st[32 + c0 + 1] + bf_hi(b.x) * st[64 + c0 + 1] + st[96 + c0 + 1];
    r0.z = bf_lo(a.y) * st[c0 + 2] + st[32 + c0 + 2] + bf_lo(b.y) * st[64 + c0 + 2] + st[96 + c0 + 2];
    r0.w = bf_hi(a.y) * st[c0 + 3] + st[32 + c0 + 3] + bf_hi(b.y) * st[64 + c0 + 3] + st[96 + c0 + 3];
    r1.x = bf_lo(a.z) * st[c0 + 4] + st[32 + c0 + 4] + bf_lo(b.z) * st[64 + c0 + 4] + st[96 + c0 + 4];
    r1.y = bf_hi(a.z) * st[c0 + 5] + st[32 + c0 + 5] + bf_hi(b.z) * st[64 + c0 + 5] + st[96 + c0 + 5];
    r1.z = bf_lo(a.w) * st[c0 + 6] + st[32 + c0 + 6] + bf_lo(b.w) * st[64 + c0 + 6] + st[96 + c0 + 6];
    r1.w = bf_hi(a.w) * st[c0 + 7] + st[32 + c0 + 7] + bf_hi(b.w) * st[64 + c0 + 7] + st[96 + c0 + 7];
    ((float4*)out)[2 * i + 0] = r0;
    ((float4*)out)[2 * i + 1] = r1;
  }
}

extern "C" void kernel_launch(void* const* d_in, const int* in_sizes, int n_in,
                              void* d_out, int out_size, void* d_ws,
                              size_t ws_size, hipStream_t stream) {
  const float* features = (const float*)d_in[0];
  const int* nbr133 = (const int*)d_in[1];
  const int* nbr313 = (const int*)d_in[2];
  const float* conv1_w = (const float*)d_in[3];
  const float* conv12_w = (const float*)d_in[4];
  const float* conv2_w = (const float*)d_in[5];
  const float* conv3_w = (const float*)d_in[6];
  const float* bn0_g = (const float*)d_in[7];
  const float* bn0_b = (const float*)d_in[8];
  const float* bn02_g = (const float*)d_in[9];
  const float* bn02_b = (const float*)d_in[10];
  const float* bn1_g = (const float*)d_in[11];
  const float* bn1_b = (const float*)d_in[12];
  const float* bn2_g = (const float*)d_in[13];
  const float* bn2_b = (const float*)d_in[14];
  float* out = (float*)d_out;

  const int n = in_sizes[0] / 16;  // 250000
  char* ws = (char*)d_ws;
  const size_t A = (size_t)n * 64 + 64;  // bf16 [n+1][32] region

  // region0: fbf ([n+1][16] bf16) overlaid later by z12 ([n][32] bf16)
  unsigned short* fbf = (unsigned short*)ws;
  unsigned short* z12 = (unsigned short*)ws;
  unsigned short* zA1 = (unsigned short*)(ws + A);
  unsigned short* zA2 = (unsigned short*)(ws + 2 * A);
  unsigned short* z3 = (unsigned short*)(ws + 3 * A);
  float* sums = (float*)(ws + 4 * A);
  // sums: 4 stat sets x NBANK banks x 64 floats:
  //   +0 z1 | +1024 z2 | +2048 z12 | +3072 z3
  uint4* tabK1 = (uint4*)(ws + 4 * A + 4 * NBANK * 64 * 4);
  uint4* tabK2 = tabK1 + 20 * 64;

  const int n8 = n * 2;  // 8-float chunks of features
  const int nc = (n8 + 255) / 256;
  // fused prep: cvt | init | tabK1 build
  prep_kernel<<<nc + 21, 256, 0, stream>>>(
      features, (uint4*)fbf, n8, conv1_w, conv2_w, tabK1, sums,
      (uint4*)(ws + (size_t)n * 32),            // fbf row n
      (uint4*)(ws + A + (size_t)n * 64),        // zA1 row n
      (uint4*)(ws + 2 * A + (size_t)n * 64),    // zA2 row n
      nc);

  const int gb = (n + 511) / 512;  // TPW=8: 512 pts/block (both convs)
  // K1: conv1 (fbf,nbr133)->zA1 || conv2 (fbf,nbr313)->zA2
  conv_mfma<true, 8><<<2 * gb, 256, 0, stream>>>(
      fbf, nbr133, tabK1, zA1, sums + 0, fbf, nbr313, tabK1 + 10 * 64, zA2,
      sums + 1024, n, gb);
  // tables for K2 (BN of K1 folded in; needs K1 stats)
  build_tab_k2<<<40, 64, 0, stream>>>(conv12_w, conv3_w, sums + 0, sums + 1024,
                                      bn0_g, bn0_b, bn1_g, bn1_b, tabK2, n);
  // K2: conv12 (bn0(zA1),nbr313)->z12 || conv3 (bn1(zA2),nbr133)->z3
  conv_mfma<false, 8><<<2 * gb, 256, 0, stream>>>(
      zA1, nbr313, tabK2, z12, sums + 2048, zA2, nbr133, tabK2 + 20 * 64, z3,
      sums + 3072, n, gb);
  // out = bn02(z12) + bn2(z3)
  final_kernel<<<1024, 256, 0, stream>>>((const uint4*)z12, (const uint4*)z3,
                                         out, sums + 2048, bn02_g, bn02_b,
                                         sums + 3072, bn2_g, bn2_b, n);
}